// Round 1
// baseline (581.599 us; speedup 1.0000x reference)
//
#include <hip/hip_runtime.h>
#include <cstdint>

// Problem constants: B=4, T=2048, D=1024, H=16, hd=64
#define MFMA16(a, b, c) __builtin_amdgcn_mfma_f32_16x16x32_bf16(a, b, c, 0, 0, 0)

typedef float  f32x4  __attribute__((ext_vector_type(4)));
typedef __bf16 bf16x8 __attribute__((ext_vector_type(8)));

__device__ __forceinline__ void gload_lds16(const void* g, const void* l) {
  // async global->LDS DMA, 16B/lane; LDS dest = wave-uniform base + lane*16
  __builtin_amdgcn_global_load_lds(
      (const __attribute__((address_space(1))) unsigned int*)(uintptr_t)g,
      (__attribute__((address_space(3))) unsigned int*)(unsigned int)(uintptr_t)l,
      16, 0, 0);
}

// ---------------- fp32 -> bf16 convert (vectorized) ----------------
__global__ void k_cvt(const float* __restrict__ in, __bf16* __restrict__ out, int n4) {
  int i = blockIdx.x * 256 + threadIdx.x;
  if (i >= n4) return;
  float4 v = reinterpret_cast<const float4*>(in)[i];
  __bf16 o[4] = {(__bf16)v.x, (__bf16)v.y, (__bf16)v.z, (__bf16)v.w};
  *reinterpret_cast<uint2*>(out + (size_t)i * 4) = *reinterpret_cast<const uint2*>(o);
}

// ---------------- fp32 [R][C] -> bf16 [C][R] tiled transpose ----------------
__global__ void k_transpose(const float* __restrict__ in, __bf16* __restrict__ out,
                            int R, int C) {
  __shared__ float tile[32][33];
  const int c0 = blockIdx.x * 32, r0 = blockIdx.y * 32;
  const int x = threadIdx.x & 31, y = threadIdx.x >> 5;  // 256 threads
#pragma unroll
  for (int i = 0; i < 4; ++i)
    tile[y + i * 8][x] = in[(size_t)(r0 + y + i * 8) * C + c0 + x];
  __syncthreads();
#pragma unroll
  for (int i = 0; i < 4; ++i)
    out[(size_t)(c0 + y + i * 8) * R + r0 + x] = (__bf16)tile[x][y + i * 8];
}

// ---------------- GEMM1: qkv = x @ W_attn + b_attn, scattered to Q/K/VT ----------------
// A: xb [8192][1024] bf16, Bt: W_attnT [3072][1024] bf16.
// Q,K written [bh][T][64]; V written TRANSPOSED [bh][64][T] (so attention needs no LDS transpose).
__global__ __launch_bounds__(256) void k_gemm_qkv(
    const __bf16* __restrict__ A, const __bf16* __restrict__ Bt,
    const float* __restrict__ bias,
    __bf16* __restrict__ Qg, __bf16* __restrict__ Kg, __bf16* __restrict__ VTg) {
  __shared__ __align__(16) __bf16 As[128 * 32];
  __shared__ __align__(16) __bf16 Bs[128 * 32];
  const int tid = threadIdx.x;
  const int w = tid >> 6, l = tid & 63;
  const int l15 = l & 15, quad = l >> 4;
  const int wr = w >> 1, wc = w & 1;
  const int bm0 = blockIdx.y * 128, bn0 = blockIdx.x * 128;

  const int rs = w * 32 + (l >> 2);  // staging row (call0); call1 adds +16
  const int kc = (l & 3) * 8;
  const __bf16* gA = A + (size_t)(bm0 + rs) * 1024 + kc;
  const __bf16* gB = Bt + (size_t)(bn0 + rs) * 1024 + kc;

  f32x4 acc[4][4] = {};

  for (int k0 = 0; k0 < 1024; k0 += 32) {
    gload_lds16(gA + k0,             As + w * 1024);
    gload_lds16(gA + k0 + 16 * 1024, As + w * 1024 + 512);
    gload_lds16(gB + k0,             Bs + w * 1024);
    gload_lds16(gB + k0 + 16 * 1024, Bs + w * 1024 + 512);
    __syncthreads();
    bf16x8 af[4], bv[4];
#pragma unroll
    for (int mt = 0; mt < 4; ++mt)
      af[mt] = *(const bf16x8*)(As + (wr * 64 + mt * 16 + l15) * 32 + quad * 8);
#pragma unroll
    for (int nt = 0; nt < 4; ++nt)
      bv[nt] = *(const bf16x8*)(Bs + (wc * 64 + nt * 16 + l15) * 32 + quad * 8);
#pragma unroll
    for (int mt = 0; mt < 4; ++mt)
#pragma unroll
      for (int nt = 0; nt < 4; ++nt)
        acc[mt][nt] = MFMA16(af[mt], bv[nt], acc[mt][nt]);
    __syncthreads();
  }

#pragma unroll
  for (int nt = 0; nt < 4; ++nt) {
    const int n = bn0 + wc * 64 + nt * 16 + l15;
    const float bvv = bias[n];
    const int which = n >> 10, rem = n & 1023;
    const int h = rem >> 6, dh = rem & 63;
#pragma unroll
    for (int mt = 0; mt < 4; ++mt) {
#pragma unroll
      for (int r = 0; r < 4; ++r) {
        const int m = bm0 + wr * 64 + mt * 16 + quad * 4 + r;
        const int bb = m >> 11, t = m & 2047;
        const int bh = bb * 16 + h;
        const __bf16 val = (__bf16)(acc[mt][nt][r] + bvv);
        if (which == 0)      Qg[((size_t)bh * 2048 + t) * 64 + dh] = val;
        else if (which == 1) Kg[((size_t)bh * 2048 + t) * 64 + dh] = val;
        else                 VTg[((size_t)bh * 64 + dh) * 2048 + t] = val;
      }
    }
  }
}

// ---------------- Flash attention: per-(bh, 128 q rows) block, 4 waves x 32 q rows ----------------
__global__ __launch_bounds__(256) void k_attn(
    const __bf16* __restrict__ Qg, const __bf16* __restrict__ Kg,
    const __bf16* __restrict__ VTg, __bf16* __restrict__ yb) {
  __shared__ __align__(16) __bf16 Ks[32 * 64];    // swizzled [kj][d]
  __shared__ __align__(16) __bf16 Vs[64 * 32];    // swizzled [d][kj]
  __shared__ __align__(16) __bf16 Ps[4][32 * 32]; // per-wave P roundtrip
  const int tid = threadIdx.x;
  const int w = tid >> 6, l = tid & 63;
  const int l15 = l & 15, quad = l >> 4;
  const int qb = blockIdx.x * 128;
  const int bh = blockIdx.y;
  const int qt0 = qb + w * 32;

  bf16x8 qf[2][2];
#pragma unroll
  for (int mt = 0; mt < 2; ++mt)
#pragma unroll
    for (int kk = 0; kk < 2; ++kk)
      qf[mt][kk] = *(const bf16x8*)(Qg + ((size_t)bh * 2048 + qt0 + mt * 16 + l15) * 64 +
                                    kk * 32 + quad * 8);

  f32x4 o[2][4] = {};
  float mstate[2][4], lstate[2][4];
#pragma unroll
  for (int mt = 0; mt < 2; ++mt)
#pragma unroll
    for (int r = 0; r < 4; ++r) { mstate[mt][r] = -1e30f; lstate[mt][r] = 0.f; }

  // staging addresses (XOR-swizzled 16B chunks; global_load_lds dest is base+lane*16)
  const int kjL = w * 8 + (l >> 3);
  const int dchK = (l & 7) ^ (kjL & 7);
  const __bf16* gK = Kg + ((size_t)bh * 2048 + kjL) * 64 + dchK * 8;
  const int dV = w * 16 + (l >> 2);
  const int kjch = (l & 3) ^ (dV & 3);
  const __bf16* gV = VTg + ((size_t)bh * 64 + dV) * 2048 + kjch * 8;

  const int lastAct = blockIdx.x * 4 + w;
  const int nkv = blockIdx.x * 4 + 4;
  const float SC = 0.18033688011112042f;  // (1/sqrt(64)) * log2(e)

  for (int it = 0; it < nkv; ++it) {
    const int kv0 = it * 32;
    gload_lds16(gK + (size_t)kv0 * 64, Ks + w * 512);
    gload_lds16(gV + kv0,              Vs + w * 512);
    __syncthreads();
    const bool act = (it <= lastAct);
    const bool diag = (it == lastAct);
    if (act) {
      bf16x8 kf[2][2];
#pragma unroll
      for (int nh = 0; nh < 2; ++nh) {
        const int kj = nh * 16 + l15;
#pragma unroll
        for (int kk = 0; kk < 2; ++kk) {
          const int ca = kj * 8 + ((kk * 4 + quad) ^ (kj & 7));
          kf[nh][kk] = *(const bf16x8*)(Ks + ca * 8);
        }
      }
#pragma unroll
      for (int mt = 0; mt < 2; ++mt) {
        f32x4 s0 = {0.f, 0.f, 0.f, 0.f}, s1 = {0.f, 0.f, 0.f, 0.f};
        s0 = MFMA16(qf[mt][0], kf[0][0], s0);
        s0 = MFMA16(qf[mt][1], kf[0][1], s0);
        s1 = MFMA16(qf[mt][0], kf[1][0], s1);
        s1 = MFMA16(qf[mt][1], kf[1][1], s1);
        float p0[4], p1[4], alpha[4];
#pragma unroll
        for (int r = 0; r < 4; ++r) {
          float v0 = s0[r] * SC, v1 = s1[r] * SC;
          if (diag) {
            const int row = qt0 + mt * 16 + quad * 4 + r;
            if (kv0 + l15 > row)      v0 = -1e30f;
            if (kv0 + 16 + l15 > row) v1 = -1e30f;
          }
          float tm = fmaxf(v0, v1);
          tm = fmaxf(tm, __shfl_xor(tm, 1, 64));
          tm = fmaxf(tm, __shfl_xor(tm, 2, 64));
          tm = fmaxf(tm, __shfl_xor(tm, 4, 64));
          tm = fmaxf(tm, __shfl_xor(tm, 8, 64));
          const float mnew = fmaxf(mstate[mt][r], tm);
          alpha[r] = exp2f(mstate[mt][r] - mnew);
          mstate[mt][r] = mnew;
          p0[r] = exp2f(v0 - mnew);
          p1[r] = exp2f(v1 - mnew);
          float rsum = p0[r] + p1[r];
          rsum += __shfl_xor(rsum, 1, 64);
          rsum += __shfl_xor(rsum, 2, 64);
          rsum += __shfl_xor(rsum, 4, 64);
          rsum += __shfl_xor(rsum, 8, 64);
          lstate[mt][r] = lstate[mt][r] * alpha[r] + rsum;
        }
#pragma unroll
        for (int nt = 0; nt < 4; ++nt)
#pragma unroll
          for (int r = 0; r < 4; ++r) o[mt][nt][r] *= alpha[r];
#pragma unroll
        for (int r = 0; r < 4; ++r) {
          Ps[w][(mt * 16 + quad * 4 + r) * 32 + l15]      = (__bf16)p0[r];
          Ps[w][(mt * 16 + quad * 4 + r) * 32 + 16 + l15] = (__bf16)p1[r];
        }
      }
    }
    __syncthreads();
    if (act) {
      bf16x8 pf[2], vf[4];
#pragma unroll
      for (int mt = 0; mt < 2; ++mt)
        pf[mt] = *(const bf16x8*)(&Ps[w][(mt * 16 + l15) * 32 + quad * 8]);
#pragma unroll
      for (int nt = 0; nt < 4; ++nt) {
        const int d = nt * 16 + l15;
        const int ca = d * 4 + (quad ^ (d & 3));
        vf[nt] = *(const bf16x8*)(Vs + ca * 8);
      }
#pragma unroll
      for (int mt = 0; mt < 2; ++mt)
#pragma unroll
        for (int nt = 0; nt < 4; ++nt)
          o[mt][nt] = MFMA16(pf[mt], vf[nt], o[mt][nt]);
    }
    __syncthreads();
  }

  const int bb = bh >> 4, h = bh & 15;
#pragma unroll
  for (int mt = 0; mt < 2; ++mt) {
#pragma unroll
    for (int r = 0; r < 4; ++r) {
      const int t = qt0 + mt * 16 + quad * 4 + r;
      const float inv = 1.0f / lstate[mt][r];
#pragma unroll
      for (int nt = 0; nt < 4; ++nt)
        yb[((size_t)(bb * 2048 + t)) * 1024 + h * 64 + nt * 16 + l15] =
            (__bf16)(o[mt][nt][r] * inv);
    }
  }
}

// ---------------- GEMM2: out = y @ W_proj + b_proj (fp32 out) ----------------
__global__ __launch_bounds__(256) void k_gemm_proj(
    const __bf16* __restrict__ A, const __bf16* __restrict__ Bt,
    const float* __restrict__ bias, float* __restrict__ out) {
  __shared__ __align__(16) __bf16 As[128 * 32];
  __shared__ __align__(16) __bf16 Bs[128 * 32];
  const int tid = threadIdx.x;
  const int w = tid >> 6, l = tid & 63;
  const int l15 = l & 15, quad = l >> 4;
  const int wr = w >> 1, wc = w & 1;
  const int bm0 = blockIdx.y * 128, bn0 = blockIdx.x * 128;

  const int rs = w * 32 + (l >> 2);
  const int kc = (l & 3) * 8;
  const __bf16* gA = A + (size_t)(bm0 + rs) * 1024 + kc;
  const __bf16* gB = Bt + (size_t)(bn0 + rs) * 1024 + kc;

  f32x4 acc[4][4] = {};

  for (int k0 = 0; k0 < 1024; k0 += 32) {
    gload_lds16(gA + k0,             As + w * 1024);
    gload_lds16(gA + k0 + 16 * 1024, As + w * 1024 + 512);
    gload_lds16(gB + k0,             Bs + w * 1024);
    gload_lds16(gB + k0 + 16 * 1024, Bs + w * 1024 + 512);
    __syncthreads();
    bf16x8 af[4], bv[4];
#pragma unroll
    for (int mt = 0; mt < 4; ++mt)
      af[mt] = *(const bf16x8*)(As + (wr * 64 + mt * 16 + l15) * 32 + quad * 8);
#pragma unroll
    for (int nt = 0; nt < 4; ++nt)
      bv[nt] = *(const bf16x8*)(Bs + (wc * 64 + nt * 16 + l15) * 32 + quad * 8);
#pragma unroll
    for (int mt = 0; mt < 4; ++mt)
#pragma unroll
      for (int nt = 0; nt < 4; ++nt)
        acc[mt][nt] = MFMA16(af[mt], bv[nt], acc[mt][nt]);
    __syncthreads();
  }

#pragma unroll
  for (int nt = 0; nt < 4; ++nt) {
    const int n = bn0 + wc * 64 + nt * 16 + l15;
    const float bvv = bias[n];
#pragma unroll
    for (int mt = 0; mt < 4; ++mt) {
#pragma unroll
      for (int r = 0; r < 4; ++r) {
        const int m = bm0 + wr * 64 + mt * 16 + quad * 4 + r;
        out[(size_t)m * 1024 + n] = acc[mt][nt][r] + bvv;
      }
    }
  }
}

extern "C" void kernel_launch(void* const* d_in, const int* in_sizes, int n_in,
                              void* d_out, int out_size, void* d_ws, size_t ws_size,
                              hipStream_t stream) {
  const float* x      = (const float*)d_in[0];
  const float* W_attn = (const float*)d_in[1];
  const float* b_attn = (const float*)d_in[2];
  const float* W_proj = (const float*)d_in[3];
  const float* b_proj = (const float*)d_in[4];
  float* out = (float*)d_out;
  char* ws = (char*)d_ws;

  // workspace layout (72 MiB total):
  __bf16* xb  = (__bf16*)(ws);                     // 16 MiB  x in bf16; later reused as y
  __bf16* WaT = (__bf16*)(ws + (16ull << 20));     //  6 MiB  W_attn^T bf16
  __bf16* WpT = (__bf16*)(ws + (22ull << 20));     //  2 MiB  W_proj^T bf16
  __bf16* Qg  = (__bf16*)(ws + (24ull << 20));     // 16 MiB  Q [bh][T][64]
  __bf16* Kg  = (__bf16*)(ws + (40ull << 20));     // 16 MiB  K [bh][T][64]
  __bf16* VTg = (__bf16*)(ws + (56ull << 20));     // 16 MiB  V^T [bh][64][T]

  k_cvt<<<8192, 256, 0, stream>>>(x, xb, 2097152);
  k_transpose<<<dim3(96, 32), 256, 0, stream>>>(W_attn, WaT, 1024, 3072);
  k_transpose<<<dim3(32, 32), 256, 0, stream>>>(W_proj, WpT, 1024, 1024);
  k_gemm_qkv<<<dim3(24, 64), 256, 0, stream>>>(xb, WaT, b_attn, Qg, Kg, VTg);
  k_attn<<<dim3(16, 64), 256, 0, stream>>>(Qg, Kg, VTg, xb /* y reuses xb */);
  k_gemm_proj<<<dim3(8, 64), 256, 0, stream>>>(xb, WpT, b_proj, out);
}

// Round 2
// 311.408 us; speedup vs baseline: 1.8676x; 1.8676x over previous
//
#include <hip/hip_runtime.h>
#include <cstdint>

// Problem constants: B=4, T=2048, D=1024, H=16, hd=64
#define MFMA16(a, b, c) __builtin_amdgcn_mfma_f32_16x16x32_bf16(a, b, c, 0, 0, 0)

typedef float  f32x4  __attribute__((ext_vector_type(4)));
typedef __bf16 bf16x8 __attribute__((ext_vector_type(8)));

__device__ __forceinline__ void gload_lds16(const void* g, const void* l) {
  // async global->LDS DMA, 16B/lane; LDS dest = wave-uniform base + lane*16
  __builtin_amdgcn_global_load_lds(
      (const __attribute__((address_space(1))) unsigned int*)(uintptr_t)g,
      (__attribute__((address_space(3))) unsigned int*)(unsigned int)(uintptr_t)l,
      16, 0, 0);
}

// ---------------- fp32 -> bf16 convert (vectorized) ----------------
__global__ void k_cvt(const float* __restrict__ in, __bf16* __restrict__ out, int n4) {
  int i = blockIdx.x * 256 + threadIdx.x;
  if (i >= n4) return;
  float4 v = reinterpret_cast<const float4*>(in)[i];
  __bf16 o[4] = {(__bf16)v.x, (__bf16)v.y, (__bf16)v.z, (__bf16)v.w};
  *reinterpret_cast<uint2*>(out + (size_t)i * 4) = *reinterpret_cast<const uint2*>(o);
}

// ---------------- fp32 [R][C] -> bf16 [C][R] tiled transpose ----------------
__global__ void k_transpose(const float* __restrict__ in, __bf16* __restrict__ out,
                            int R, int C) {
  __shared__ float tile[32][33];
  const int c0 = blockIdx.x * 32, r0 = blockIdx.y * 32;
  const int x = threadIdx.x & 31, y = threadIdx.x >> 5;  // 256 threads
#pragma unroll
  for (int i = 0; i < 4; ++i)
    tile[y + i * 8][x] = in[(size_t)(r0 + y + i * 8) * C + c0 + x];
  __syncthreads();
#pragma unroll
  for (int i = 0; i < 4; ++i)
    out[(size_t)(c0 + y + i * 8) * R + r0 + x] = (__bf16)tile[x][y + i * 8];
}

// ---------------- GEMM1: qkv = x @ W_attn + b_attn, scattered to Q/K/VT ----------------
__global__ __launch_bounds__(256) void k_gemm_qkv(
    const __bf16* __restrict__ A, const __bf16* __restrict__ Bt,
    const float* __restrict__ bias,
    __bf16* __restrict__ Qg, __bf16* __restrict__ Kg, __bf16* __restrict__ VTg) {
  __shared__ __align__(16) __bf16 As[128 * 32];
  __shared__ __align__(16) __bf16 Bs[128 * 32];
  const int tid = threadIdx.x;
  const int w = tid >> 6, l = tid & 63;
  const int l15 = l & 15, quad = l >> 4;
  const int wr = w >> 1, wc = w & 1;
  const int bm0 = blockIdx.y * 128, bn0 = blockIdx.x * 128;

  const int rs = w * 32 + (l >> 2);
  const int kc = (l & 3) * 8;
  const __bf16* gA = A + (size_t)(bm0 + rs) * 1024 + kc;
  const __bf16* gB = Bt + (size_t)(bn0 + rs) * 1024 + kc;

  f32x4 acc[4][4] = {};

  for (int k0 = 0; k0 < 1024; k0 += 32) {
    gload_lds16(gA + k0,             As + w * 1024);
    gload_lds16(gA + k0 + 16 * 1024, As + w * 1024 + 512);
    gload_lds16(gB + k0,             Bs + w * 1024);
    gload_lds16(gB + k0 + 16 * 1024, Bs + w * 1024 + 512);
    __syncthreads();
    bf16x8 af[4], bv[4];
#pragma unroll
    for (int mt = 0; mt < 4; ++mt)
      af[mt] = *(const bf16x8*)(As + (wr * 64 + mt * 16 + l15) * 32 + quad * 8);
#pragma unroll
    for (int nt = 0; nt < 4; ++nt)
      bv[nt] = *(const bf16x8*)(Bs + (wc * 64 + nt * 16 + l15) * 32 + quad * 8);
#pragma unroll
    for (int mt = 0; mt < 4; ++mt)
#pragma unroll
      for (int nt = 0; nt < 4; ++nt)
        acc[mt][nt] = MFMA16(af[mt], bv[nt], acc[mt][nt]);
    __syncthreads();
  }

#pragma unroll
  for (int nt = 0; nt < 4; ++nt) {
    const int n = bn0 + wc * 64 + nt * 16 + l15;
    const float bvv = bias[n];
    const int which = n >> 10, rem = n & 1023;
    const int h = rem >> 6, dh = rem & 63;
#pragma unroll
    for (int mt = 0; mt < 4; ++mt) {
#pragma unroll
      for (int r = 0; r < 4; ++r) {
        const int m = bm0 + wr * 64 + mt * 16 + quad * 4 + r;
        const int bb = m >> 11, t = m & 2047;
        const int bh = bb * 16 + h;
        const __bf16 val = (__bf16)(acc[mt][nt][r] + bvv);
        if (which == 0)      Qg[((size_t)bh * 2048 + t) * 64 + dh] = val;
        else if (which == 1) Kg[((size_t)bh * 2048 + t) * 64 + dh] = val;
        else                 VTg[((size_t)bh * 64 + dh) * 2048 + t] = val;
      }
    }
  }
}

// ---------------- Flash attention, S^T formulation ----------------
// Grid (8, 64). Block = 4 waves, 128 q rows per q-tile; each block processes
// q-tiles {x, 15-x} -> exactly 34 kv-64 iterations per block (perfect balance).
// S^T = K·Q^T puts q in lane&15: softmax row-reduce = 16 in-reg ops + 2 shuffles.
// y^T = V^T·P^T; P^T LDS roundtrip per-wave (stride 72 -> 2-way conflicts, free).
__global__ __launch_bounds__(256) void k_attn(
    const __bf16* __restrict__ Qg, const __bf16* __restrict__ Kg,
    const __bf16* __restrict__ VTg, __bf16* __restrict__ yb) {
  __shared__ __align__(16) __bf16 Ks[2][64 * 64];   // [kv][d], 16B-chunk XOR swizzle
  __shared__ __align__(16) __bf16 Vs[2][64 * 64];   // [d][kv], 16B-chunk XOR swizzle
  __shared__ __align__(16) __bf16 Ps[4][32 * 72];   // per-wave P^T as [q][kv], stride 72
  const int tid = threadIdx.x;
  const int w = tid >> 6, l = tid & 63;
  const int l15 = l & 15, quad = l >> 4;
  const int bh = blockIdx.y;
  const int bb = bh >> 4, h = bh & 15;
  const float SC = 0.18033688011112042f;  // (1/sqrt(64)) * log2(e)

  // staging lane addresses (fixed for whole kernel)
  const int rowL = w * 8 + (l >> 3);             // 0..31 within a 32-row call
  const int chK = (l & 7) ^ (rowL & 7);          // XOR swizzle on 16B chunks
  const __bf16* gK = Kg + ((size_t)bh * 2048 + rowL) * 64 + chK * 8;
  const __bf16* gV = VTg + ((size_t)bh * 64 + rowL) * 2048 + chK * 8;
  __bf16* Psw = Ps[w];

  for (int seg = 0; seg < 2; ++seg) {
    const int qtile = seg == 0 ? blockIdx.x : 15 - blockIdx.x;
    const int qt0 = qtile * 128 + w * 32;
    const int ntiles = 2 * qtile + 2;
    const int myLast = (qt0 + 31) >> 6;

    __syncthreads();  // protect LDS reuse across segments

    // Q fragments (register-resident): B-operand layout q=lane&15, d=k
    bf16x8 qf[2][2];
#pragma unroll
    for (int qt = 0; qt < 2; ++qt)
#pragma unroll
      for (int kk = 0; kk < 2; ++kk)
        qf[qt][kk] = *(const bf16x8*)(Qg + ((size_t)bh * 2048 + qt0 + qt * 16 + l15) * 64 +
                                      kk * 32 + quad * 8);

    f32x4 o[4][2] = {};
    float mstate[2] = {-1e30f, -1e30f}, lstate[2] = {0.f, 0.f};

    // prefetch tile 0 into buf 0
    {
      gload_lds16(gK,             Ks[0] + w * 512);
      gload_lds16(gK + 32 * 64,   Ks[0] + 2048 + w * 512);
      gload_lds16(gV,             Vs[0] + w * 512);
      gload_lds16(gV + 32 * 2048, Vs[0] + 2048 + w * 512);
    }

    for (int it = 0; it < ntiles; ++it) {
      __syncthreads();  // tile `it` staged (barrier drains vmcnt); prev-buf reads done
      if (it + 1 < ntiles) {
        const int kv0 = (it + 1) * 64;
        __bf16* KsB = Ks[(it + 1) & 1];
        __bf16* VsB = Vs[(it + 1) & 1];
        gload_lds16(gK + (size_t)kv0 * 64,           KsB + w * 512);
        gload_lds16(gK + (size_t)kv0 * 64 + 32 * 64, KsB + 2048 + w * 512);
        gload_lds16(gV + kv0,                        VsB + w * 512);
        gload_lds16(gV + kv0 + 32 * 2048,            VsB + 2048 + w * 512);
      }
      if (it <= myLast) {
        const __bf16* KsB = Ks[it & 1];
        const __bf16* VsB = Vs[it & 1];
        const int kv0 = it * 64;
        const bool diag = (it == myLast);
        // K A-fragments: kv=lane&15 (+16*kvt), k=d
        bf16x8 kf[4][2];
#pragma unroll
        for (int kvt = 0; kvt < 4; ++kvt)
#pragma unroll
          for (int kk = 0; kk < 2; ++kk)
            kf[kvt][kk] = *(const bf16x8*)(KsB + (kvt * 16 + l15) * 64 +
                                           (((kk * 4 + quad) ^ (l15 & 7)) * 8));
        // S^T tiles: D[kv][q], kv = kvt*16+quad*4+r, q = qt*16+l15
        f32x4 st[4][2] = {};
#pragma unroll
        for (int kvt = 0; kvt < 4; ++kvt)
#pragma unroll
          for (int qt = 0; qt < 2; ++qt) {
            st[kvt][qt] = MFMA16(kf[kvt][0], qf[qt][0], st[kvt][qt]);
            st[kvt][qt] = MFMA16(kf[kvt][1], qf[qt][1], st[kvt][qt]);
          }
        // online softmax per q (q = qt*16 + l15, per-lane state)
#pragma unroll
        for (int qt = 0; qt < 2; ++qt) {
          const int qrow = qt0 + qt * 16 + l15;
          float sc[4][4];
          float mx = -1e30f;
#pragma unroll
          for (int kvt = 0; kvt < 4; ++kvt)
#pragma unroll
            for (int r = 0; r < 4; ++r) {
              float s = st[kvt][qt][r] * SC;
              if (diag && (kv0 + kvt * 16 + quad * 4 + r > qrow)) s = -1e30f;
              sc[kvt][r] = s;
              mx = fmaxf(mx, s);
            }
          mx = fmaxf(mx, __shfl_xor(mx, 16, 64));
          mx = fmaxf(mx, __shfl_xor(mx, 32, 64));
          const float mnew = fmaxf(mstate[qt], mx);
          const float alpha = exp2f(mstate[qt] - mnew);
          mstate[qt] = mnew;
          float sum = 0.f;
#pragma unroll
          for (int kvt = 0; kvt < 4; ++kvt) {
            float p0 = exp2f(sc[kvt][0] - mnew), p1 = exp2f(sc[kvt][1] - mnew);
            float p2 = exp2f(sc[kvt][2] - mnew), p3 = exp2f(sc[kvt][3] - mnew);
            sum += (p0 + p1) + (p2 + p3);
            __bf16 pk[4] = {(__bf16)p0, (__bf16)p1, (__bf16)p2, (__bf16)p3};
            // P^T as Ps[q][kv]: two b32 writes (kv pairs are adjacent)
            *(uint32_t*)(Psw + (qt * 16 + l15) * 72 + kvt * 16 + quad * 4)     = *(uint32_t*)&pk[0];
            *(uint32_t*)(Psw + (qt * 16 + l15) * 72 + kvt * 16 + quad * 4 + 2) = *(uint32_t*)&pk[2];
          }
          sum += __shfl_xor(sum, 16, 64);
          sum += __shfl_xor(sum, 32, 64);
          lstate[qt] = lstate[qt] * alpha + sum;
#pragma unroll
          for (int dt = 0; dt < 4; ++dt) o[dt][qt] *= alpha;
        }
        // PV: y^T tiles, A = V^T (d=lane&15, k=kv), B = P^T (q=lane&15, k=kv)
        // per-wave LDS roundtrip: compiler inserts lgkmcnt wait, no barrier needed
        bf16x8 pf[2][2], vf[4][2];
#pragma unroll
        for (int qt = 0; qt < 2; ++qt)
#pragma unroll
          for (int kk = 0; kk < 2; ++kk)
            pf[qt][kk] = *(const bf16x8*)(Psw + (qt * 16 + l15) * 72 + kk * 32 + quad * 8);
#pragma unroll
        for (int dt = 0; dt < 4; ++dt)
#pragma unroll
          for (int kk = 0; kk < 2; ++kk)
            vf[dt][kk] = *(const bf16x8*)(VsB + (dt * 16 + l15) * 64 +
                                          (((kk * 4 + quad) ^ (l15 & 7)) * 8));
#pragma unroll
        for (int dt = 0; dt < 4; ++dt)
#pragma unroll
          for (int qt = 0; qt < 2; ++qt) {
            o[dt][qt] = MFMA16(vf[dt][0], pf[qt][0], o[dt][qt]);
            o[dt][qt] = MFMA16(vf[dt][1], pf[qt][1], o[dt][qt]);
          }
      }
    }

    // epilogue: y^T C-layout -> y[t][h*64+d], 8B packed stores
#pragma unroll
    for (int qt = 0; qt < 2; ++qt) {
      const float inv = 1.0f / lstate[qt];
      const int t = qt0 + qt * 16 + l15;
#pragma unroll
      for (int dt = 0; dt < 4; ++dt) {
        __bf16 ov[4];
#pragma unroll
        for (int r = 0; r < 4; ++r) ov[r] = (__bf16)(o[dt][qt][r] * inv);
        *(uint2*)(yb + ((size_t)(bb * 2048 + t)) * 1024 + h * 64 + dt * 16 + quad * 4) =
            *(uint2*)ov;
      }
    }
  }
}

// ---------------- GEMM2: out = y @ W_proj + b_proj (fp32 out) ----------------
__global__ __launch_bounds__(256) void k_gemm_proj(
    const __bf16* __restrict__ A, const __bf16* __restrict__ Bt,
    const float* __restrict__ bias, float* __restrict__ out) {
  __shared__ __align__(16) __bf16 As[128 * 32];
  __shared__ __align__(16) __bf16 Bs[128 * 32];
  const int tid = threadIdx.x;
  const int w = tid >> 6, l = tid & 63;
  const int l15 = l & 15, quad = l >> 4;
  const int wr = w >> 1, wc = w & 1;
  const int bm0 = blockIdx.y * 128, bn0 = blockIdx.x * 128;

  const int rs = w * 32 + (l >> 2);
  const int kc = (l & 3) * 8;
  const __bf16* gA = A + (size_t)(bm0 + rs) * 1024 + kc;
  const __bf16* gB = Bt + (size_t)(bn0 + rs) * 1024 + kc;

  f32x4 acc[4][4] = {};

  for (int k0 = 0; k0 < 1024; k0 += 32) {
    gload_lds16(gA + k0,             As + w * 1024);
    gload_lds16(gA + k0 + 16 * 1024, As + w * 1024 + 512);
    gload_lds16(gB + k0,             Bs + w * 1024);
    gload_lds16(gB + k0 + 16 * 1024, Bs + w * 1024 + 512);
    __syncthreads();
    bf16x8 af[4], bv[4];
#pragma unroll
    for (int mt = 0; mt < 4; ++mt)
      af[mt] = *(const bf16x8*)(As + (wr * 64 + mt * 16 + l15) * 32 + quad * 8);
#pragma unroll
    for (int nt = 0; nt < 4; ++nt)
      bv[nt] = *(const bf16x8*)(Bs + (wc * 64 + nt * 16 + l15) * 32 + quad * 8);
#pragma unroll
    for (int mt = 0; mt < 4; ++mt)
#pragma unroll
      for (int nt = 0; nt < 4; ++nt)
        acc[mt][nt] = MFMA16(af[mt], bv[nt], acc[mt][nt]);
    __syncthreads();
  }

#pragma unroll
  for (int nt = 0; nt < 4; ++nt) {
    const int n = bn0 + wc * 64 + nt * 16 + l15;
    const float bvv = bias[n];
#pragma unroll
    for (int mt = 0; mt < 4; ++mt) {
#pragma unroll
      for (int r = 0; r < 4; ++r) {
        const int m = bm0 + wr * 64 + mt * 16 + quad * 4 + r;
        out[(size_t)m * 1024 + n] = acc[mt][nt][r] + bvv;
      }
    }
  }
}

extern "C" void kernel_launch(void* const* d_in, const int* in_sizes, int n_in,
                              void* d_out, int out_size, void* d_ws, size_t ws_size,
                              hipStream_t stream) {
  const float* x      = (const float*)d_in[0];
  const float* W_attn = (const float*)d_in[1];
  const float* b_attn = (const float*)d_in[2];
  const float* W_proj = (const float*)d_in[3];
  const float* b_proj = (const float*)d_in[4];
  float* out = (float*)d_out;
  char* ws = (char*)d_ws;

  __bf16* xb  = (__bf16*)(ws);                     // 16 MiB  x bf16; later reused as y
  __bf16* WaT = (__bf16*)(ws + (16ull << 20));     //  6 MiB  W_attn^T bf16
  __bf16* WpT = (__bf16*)(ws + (22ull << 20));     //  2 MiB  W_proj^T bf16
  __bf16* Qg  = (__bf16*)(ws + (24ull << 20));     // 16 MiB  Q [bh][T][64]
  __bf16* Kg  = (__bf16*)(ws + (40ull << 20));     // 16 MiB  K [bh][T][64]
  __bf16* VTg = (__bf16*)(ws + (56ull << 20));     // 16 MiB  V^T [bh][64][T]

  k_cvt<<<8192, 256, 0, stream>>>(x, xb, 2097152);
  k_transpose<<<dim3(96, 32), 256, 0, stream>>>(W_attn, WaT, 1024, 3072);
  k_transpose<<<dim3(32, 32), 256, 0, stream>>>(W_proj, WpT, 1024, 1024);
  k_gemm_qkv<<<dim3(24, 64), 256, 0, stream>>>(xb, WaT, b_attn, Qg, Kg, VTg);
  k_attn<<<dim3(8, 64), 256, 0, stream>>>(Qg, Kg, VTg, xb /* y reuses xb */);
  k_gemm_proj<<<dim3(8, 64), 256, 0, stream>>>(xb, WpT, b_proj, out);
}